// Round 3
// baseline (240.944 us; speedup 1.0000x reference)
//
#include <hip/hip_runtime.h>

// CovLayer: X [B=64, C=256, T=2048] fp32 -> cov [B, 256, 256] fp32
// cov = (Sxy - Sx*Sy/T) / T
// Round 3: LDS-FREE main loop. 16x16x32 MFMA A/B fragments are loaded
// DIRECTLY from global (fragment layout == coalesced 16-row load), so the
// K-loop has no barriers, no LDS traffic, no bank conflicts. Symmetric:
// only 10 of 16 upper 64x64 tiles computed, mirrored on store. Split-K=2
// across the block's 2 waves; small LDS reduction in the epilogue only.

#define NB 64
#define NC 256
#define NT 2048
#define KITER 32   // (NT/2) / 32 k-elements per iteration

typedef __bf16 bf16x8 __attribute__((ext_vector_type(8)));
typedef float  f32x8  __attribute__((ext_vector_type(8)));
typedef float  f32x4  __attribute__((ext_vector_type(4)));

__global__ __launch_bounds__(128, 2) void cov_kernel(const float* __restrict__ X,
                                                     float* __restrict__ out) {
    // 640 blocks = 8 xcd * 8 batch-groups * 10 upper tiles.
    const int bid  = blockIdx.x;
    const int xcd  = bid & 7;
    const int s    = bid >> 3;           // 0..79
    const int b    = xcd + 8 * (s / 10); // same batch -> same XCD for L2 locality
    const int tile = s % 10;
    int tm, tn;                          // upper-triangle 4x4 tile coords (wave-uniform)
    if (tile < 4)      { tm = 0; tn = tile; }
    else if (tile < 7) { tm = 1; tn = tile - 3; }
    else if (tile < 9) { tm = 2; tn = tile - 5; }
    else               { tm = 3; tn = 3; }
    const int row0 = tm * 64, col0 = tn * 64;

    const float* __restrict__ Xb = X + (size_t)b * (NC * NT);

    const int t    = threadIdx.x;        // 128 threads = 2 waves (k-split halves)
    const int lane = t & 63;
    const int wave = t >> 6;
    const int quad = lane >> 4;
    const int l16  = lane & 15;

    // Direct-fragment pointers: lane (l16, quad) owns row l16, k-chunk quad*8.
    const float* baseA = Xb + (size_t)(row0 + l16) * NT + wave * (NT / 2) + quad * 8;
    const float* baseB = Xb + (size_t)(col0 + l16) * NT + wave * (NT / 2) + quad * 8;

    f32x4 acc[4][4], accRS[4], accCS[4];
#pragma unroll
    for (int i = 0; i < 4; ++i) {
        accRS[i] = (f32x4){0.f, 0.f, 0.f, 0.f};
        accCS[i] = (f32x4){0.f, 0.f, 0.f, 0.f};
#pragma unroll
        for (int j = 0; j < 4; ++j) acc[i][j] = (f32x4){0.f, 0.f, 0.f, 0.f};
    }

    const bf16x8 ones = {(__bf16)1.0f, (__bf16)1.0f, (__bf16)1.0f, (__bf16)1.0f,
                         (__bf16)1.0f, (__bf16)1.0f, (__bf16)1.0f, (__bf16)1.0f};

    // Prefetch iteration 0 (8 x f32x8 = 16 dwordx4 in flight).
    f32x8 vA[4], vB[4];
#pragma unroll
    for (int i = 0; i < 4; ++i) {
        vA[i] = *(const f32x8*)(baseA + (size_t)i * 16 * NT);
        vB[i] = *(const f32x8*)(baseB + (size_t)i * 16 * NT);
    }

#pragma unroll 1
    for (int it = 0; it < KITER; ++it) {
        bf16x8 aF[4], bF[4];
#pragma unroll
        for (int i = 0; i < 4; ++i) {
            aF[i] = __builtin_convertvector(vA[i], bf16x8);
            bF[i] = __builtin_convertvector(vB[i], bf16x8);
        }
        if (it + 1 < KITER) {           // issue next iter's loads; overlap MFMA burst
            const int off = (it + 1) * 32;
#pragma unroll
            for (int i = 0; i < 4; ++i) {
                vA[i] = *(const f32x8*)(baseA + (size_t)i * 16 * NT + off);
                vB[i] = *(const f32x8*)(baseB + (size_t)i * 16 * NT + off);
            }
        }
#pragma unroll
        for (int mt = 0; mt < 4; ++mt) {
            accRS[mt] = __builtin_amdgcn_mfma_f32_16x16x32_bf16(aF[mt], ones, accRS[mt], 0, 0, 0);
#pragma unroll
            for (int nt = 0; nt < 4; ++nt)
                acc[mt][nt] = __builtin_amdgcn_mfma_f32_16x16x32_bf16(aF[mt], bF[nt], acc[mt][nt], 0, 0, 0);
        }
#pragma unroll
        for (int nt = 0; nt < 4; ++nt)
            accCS[nt] = __builtin_amdgcn_mfma_f32_16x16x32_bf16(ones, bF[nt], accCS[nt], 0, 0, 0);
    }

    // Cross-wave (split-K) reduction through LDS, epilogue only.
    __shared__ float red[64 * 65];      // stride 65: quad varies bank -> conflict-light
    __shared__ float rsum[64];
    __shared__ float csum[64];

    if (wave == 0) {
#pragma unroll
        for (int mt = 0; mt < 4; ++mt)
#pragma unroll
            for (int nt = 0; nt < 4; ++nt)
#pragma unroll
                for (int r = 0; r < 4; ++r)
                    red[(mt * 16 + quad * 4 + r) * 65 + nt * 16 + l16] = acc[mt][nt][r];
        if (l16 == 0) {
#pragma unroll
            for (int mt = 0; mt < 4; ++mt)
#pragma unroll
                for (int r = 0; r < 4; ++r)
                    rsum[mt * 16 + quad * 4 + r] = accRS[mt][r];
        }
        if (quad == 0) {
#pragma unroll
            for (int nt = 0; nt < 4; ++nt)
                csum[nt * 16 + l16] = accCS[nt][0];
        }
    }
    __syncthreads();

    if (wave == 1) {
        const float invT = 1.0f / NT;
        float* __restrict__ outB = out + (size_t)b * (NC * NC);
#pragma unroll
        for (int mt = 0; mt < 4; ++mt) {
#pragma unroll
            for (int nt = 0; nt < 4; ++nt) {
#pragma unroll
                for (int r = 0; r < 4; ++r) {
                    const int rl = mt * 16 + quad * 4 + r;
                    const int cl = nt * 16 + l16;
                    const float tot = red[rl * 65 + cl] + acc[mt][nt][r];
                    const float rsT = rsum[rl] + accRS[mt][r];
                    const float csT = csum[cl] + accCS[nt][0];
                    const float val = (tot - rsT * csT * invT) * invT;
                    outB[(size_t)(row0 + rl) * NC + (col0 + cl)] = val;
                    outB[(size_t)(col0 + cl) * NC + (row0 + rl)] = val;  // mirror
                }
            }
        }
    }
}

extern "C" void kernel_launch(void* const* d_in, const int* in_sizes, int n_in,
                              void* d_out, int out_size, void* d_ws, size_t ws_size,
                              hipStream_t stream) {
    const float* X = (const float*)d_in[0];
    float* out = (float*)d_out;
    (void)in_sizes; (void)n_in; (void)out_size; (void)d_ws; (void)ws_size;
    cov_kernel<<<640, 128, 0, stream>>>(X, out);
}

// Round 4
// 205.446 us; speedup vs baseline: 1.1728x; 1.1728x over previous
//
#include <hip/hip_runtime.h>

// CovLayer: X [B=64, C=256, T=2048] fp32 -> cov [B, 256, 256] fp32
// cov = (Sxy - Sx*Sy/T) / T   via bf16 MFMA Gram + MFMA-ones row/col sums.
// Round 4: 128x128 tile per block (4/batch, batch->XCD swizzle), 512 threads
// = 8 waves: 2x2 spatial (64x64/wave) x in-block split-K 2. Double-buffered
// LDS staging (one barrier/iter), global prefetch depth 2. Epilogue reduces
// the two K-halves through LDS scratch overlaying the staging buffers.

#define NB 64
#define NC 256
#define NT 2048
#define NITER 32        // (NT/2) / 32 per K-half

typedef __bf16 bf16x8 __attribute__((ext_vector_type(8)));
typedef float  f32x8  __attribute__((ext_vector_type(8)));
typedef float  f32x4  __attribute__((ext_vector_type(4)));

__global__ __launch_bounds__(512, 2) void cov_kernel(const float* __restrict__ X,
                                                     float* __restrict__ out) {
    // Staging: [A/B][buf 0/1][half 0/1][128*32 bf16]  = 64 KB.
    // Epilogue overlay: red[4][64*65] + rs[4*64] + cs[4*64] floats = 68.6 KB.
    __shared__ __align__(16) unsigned char smem[68608];
    __bf16* sAB  = (__bf16*)smem;
    float*  redF = (float*)smem;

    const int bid  = blockIdx.x;
    const int xcd  = bid & 7;
    const int g    = bid >> 3;           // 0..31
    const int b    = xcd + 8 * (g >> 2); // batch: 4 consecutive tiles share XCD
    const int q    = g & 3;              // which 128x128 quadrant of 256x256
    const int row0 = (q >> 1) * 128, col0 = (q & 1) * 128;

    const float* __restrict__ Xb = X + (size_t)b * (NC * NT);

    const int t    = threadIdx.x;        // 512 threads = 8 waves
    const int lane = t & 63;
    const int wave = t >> 6;
    const int h    = wave >> 2;          // K-half: [h*1024, h*1024+1024)
    const int wq   = wave & 3;
    const int wm   = wq >> 1, wn = wq & 1;   // 2x2 waves, 64x64 each
    const int quad = lane >> 4;
    const int l16  = lane & 15;

    // Staging: u = t&255 within half h. Thread u: rows sr and sr+64, k-chunk sc.
    const int u  = t & 255;
    const int sr = u >> 2;               // 0..63
    const int sc = (u & 3) * 8;          // 4 lanes cover 32 contiguous floats/row
    const float* gA0 = Xb + (size_t)(row0 + sr) * NT + h * (NT / 2) + sc;
    const float* gA1 = gA0 + (size_t)64 * NT;
    const float* gB0 = Xb + (size_t)(col0 + sr) * NT + h * (NT / 2) + sc;
    const float* gB1 = gB0 + (size_t)64 * NT;

    // LDS staging bases (elements) for this thread's half.
    __bf16* sA[2] = { sAB + (0 * 2 + h) * 4096, sAB + (1 * 2 + h) * 4096 };
    __bf16* sB[2] = { sAB + 16384 + (0 * 2 + h) * 4096, sAB + 16384 + (1 * 2 + h) * 4096 };
    const int woff = sr * 32 + sc;       // write offset; second row at +2048

    f32x4 acc[4][4], accRS[4], accCS[4];
#pragma unroll
    for (int i = 0; i < 4; ++i) {
        accRS[i] = (f32x4){0.f, 0.f, 0.f, 0.f};
        accCS[i] = (f32x4){0.f, 0.f, 0.f, 0.f};
#pragma unroll
        for (int j = 0; j < 4; ++j) acc[i][j] = (f32x4){0.f, 0.f, 0.f, 0.f};
    }
    const bf16x8 ones = {(__bf16)1.0f, (__bf16)1.0f, (__bf16)1.0f, (__bf16)1.0f,
                         (__bf16)1.0f, (__bf16)1.0f, (__bf16)1.0f, (__bf16)1.0f};

    // Prologue: stage iter 0 into buf0, prefetch iter 1 into regs.
    f32x8 pA0 = *(const f32x8*)gA0;
    f32x8 pA1 = *(const f32x8*)gA1;
    f32x8 pB0 = *(const f32x8*)gB0;
    f32x8 pB1 = *(const f32x8*)gB1;
    *(bf16x8*)(sA[0] + woff)        = __builtin_convertvector(pA0, bf16x8);
    *(bf16x8*)(sA[0] + woff + 2048) = __builtin_convertvector(pA1, bf16x8);
    *(bf16x8*)(sB[0] + woff)        = __builtin_convertvector(pB0, bf16x8);
    *(bf16x8*)(sB[0] + woff + 2048) = __builtin_convertvector(pB1, bf16x8);
    pA0 = *(const f32x8*)(gA0 + 32);
    pA1 = *(const f32x8*)(gA1 + 32);
    pB0 = *(const f32x8*)(gB0 + 32);
    pB1 = *(const f32x8*)(gB1 + 32);
    __syncthreads();

    const int aBase = (wm * 64 + l16) * 32 + quad * 8;   // + mt*16*32
    const int bBase = (wn * 64 + l16) * 32 + quad * 8;

#pragma unroll 2
    for (int k = 0; k < NITER; ++k) {
        const int cur = k & 1, nxt = cur ^ 1;

        // Stage G_{k+1} (in regs) into the other buffer; its last readers
        // finished before the barrier that ended iteration k-1.
        if (k + 1 < NITER) {
            *(bf16x8*)(sA[nxt] + woff)        = __builtin_convertvector(pA0, bf16x8);
            *(bf16x8*)(sA[nxt] + woff + 2048) = __builtin_convertvector(pA1, bf16x8);
            *(bf16x8*)(sB[nxt] + woff)        = __builtin_convertvector(pB0, bf16x8);
            *(bf16x8*)(sB[nxt] + woff + 2048) = __builtin_convertvector(pB1, bf16x8);
        }
        // Prefetch G_{k+2}: consumed one full iteration from now.
        if (k + 2 < NITER) {
            pA0 = *(const f32x8*)(gA0 + (k + 2) * 32);
            pA1 = *(const f32x8*)(gA1 + (k + 2) * 32);
            pB0 = *(const f32x8*)(gB0 + (k + 2) * 32);
            pB1 = *(const f32x8*)(gB1 + (k + 2) * 32);
        }

        bf16x8 aF[4], bF[4];
#pragma unroll
        for (int mt = 0; mt < 4; ++mt)
            aF[mt] = *(const bf16x8*)(sA[cur] + aBase + mt * 16 * 32);
#pragma unroll
        for (int nt = 0; nt < 4; ++nt)
            bF[nt] = *(const bf16x8*)(sB[cur] + bBase + nt * 16 * 32);

#pragma unroll
        for (int mt = 0; mt < 4; ++mt) {
            accRS[mt] = __builtin_amdgcn_mfma_f32_16x16x32_bf16(aF[mt], ones, accRS[mt], 0, 0, 0);
#pragma unroll
            for (int nt = 0; nt < 4; ++nt)
                acc[mt][nt] = __builtin_amdgcn_mfma_f32_16x16x32_bf16(aF[mt], bF[nt], acc[mt][nt], 0, 0, 0);
        }
#pragma unroll
        for (int nt = 0; nt < 4; ++nt)
            accCS[nt] = __builtin_amdgcn_mfma_f32_16x16x32_bf16(ones, bF[nt], accCS[nt], 0, 0, 0);

        __syncthreads();   // one barrier per iteration (dbuf decouples the rest)
    }

    // Epilogue: combine the two K-halves. h=1 dumps to LDS; h=0 reduces+stores.
    float* red = redF + wq * (64 * 65);
    float* rs  = redF + 4 * (64 * 65);       // [4][64]
    float* cs  = rs + 256;                   // [4][64]

    if (h == 1) {
#pragma unroll
        for (int mt = 0; mt < 4; ++mt)
#pragma unroll
            for (int nt = 0; nt < 4; ++nt)
#pragma unroll
                for (int r = 0; r < 4; ++r)
                    red[(mt * 16 + quad * 4 + r) * 65 + nt * 16 + l16] = acc[mt][nt][r];
        if (l16 == 0) {
#pragma unroll
            for (int mt = 0; mt < 4; ++mt)
#pragma unroll
                for (int r = 0; r < 4; ++r)
                    rs[wq * 64 + mt * 16 + quad * 4 + r] = accRS[mt][r];
        }
        if (quad == 0) {
#pragma unroll
            for (int nt = 0; nt < 4; ++nt)
                cs[wq * 64 + nt * 16 + l16] = accCS[nt][0];
        }
    }
    __syncthreads();

    if (h == 0) {
        const float invT = 1.0f / NT;
        float* __restrict__ outB = out + (size_t)b * (NC * NC);
#pragma unroll
        for (int mt = 0; mt < 4; ++mt) {
#pragma unroll
            for (int nt = 0; nt < 4; ++nt) {
#pragma unroll
                for (int r = 0; r < 4; ++r) {
                    const int R = mt * 16 + quad * 4 + r;
                    const int C = nt * 16 + l16;
                    const float tot = red[R * 65 + C] + acc[mt][nt][r];
                    const float Sx  = rs[wq * 64 + R] + accRS[mt][r];
                    const float Sy  = cs[wq * 64 + C] + accCS[nt][0];
                    outB[(size_t)(row0 + wm * 64 + R) * NC + (col0 + wn * 64 + C)] =
                        (tot - Sx * Sy * invT) * invT;
                }
            }
        }
    }
}

extern "C" void kernel_launch(void* const* d_in, const int* in_sizes, int n_in,
                              void* d_out, int out_size, void* d_ws, size_t ws_size,
                              hipStream_t stream) {
    const float* X = (const float*)d_in[0];
    float* out = (float*)d_out;
    (void)in_sizes; (void)n_in; (void)out_size; (void)d_ws; (void)ws_size;
    cov_kernel<<<256, 512, 0, stream>>>(X, out);
}